// Round 2
// baseline (139.093 us; speedup 1.0000x reference)
//
#include <hip/hip_runtime.h>
#include <hip/hip_bf16.h>

// Problem: B=2, N=1024, Fin=64, Fout=32 — ALL fp32 (per reference dtypes).
// Degenerate-score GAT: the buggy concat+view collapses scores to
//   i<512 : two distinct values per row -> pair-softmax weights w0,w1
//   i>=512: one shared score row -> one shared att@vv vector r per batch
// Only adj@vv is real matmul work.

#define ALPHA 0.01f

__device__ __forceinline__ float leaky(float x){ return x >= 0.f ? x : ALPHA*x; }

// ---------------- K1: projections + row scalars -------------------------
// grid 256 blocks x 256 thr; 8 rows/block, 32 threads (one per out-feature)/row.
// Writes vv (fp32), p = h.(a1+a2), q1 = kk.a1, q2 = kk.a2.
__global__ __launch_bounds__(256) void k_proj(
    const float* __restrict__ inp,
    const float* __restrict__ kin,
    const float* __restrict__ vin,
    const float* __restrict__ W,
    const float* __restrict__ Wk,
    const float* __restrict__ Wv,
    const float* __restrict__ a,
    float* __restrict__ vv, float* __restrict__ p,
    float* __restrict__ q1, float* __restrict__ q2)
{
    int tid = threadIdx.x;
    int row = blockIdx.x*8 + (tid>>5);   // [0, 2048)
    int f   = tid & 31;
    const float* xrow = inp + row*64;
    const float* krow = kin + row*64;
    const float* vrow = vin + row*64;
    float hacc=0.f, kacc=0.f, vacc=0.f;
    #pragma unroll 8
    for (int c=0; c<64; c++){
        float xc = xrow[c], kc = krow[c], vc = vrow[c];
        hacc += xc * W [c*32+f];
        kacc += kc * Wk[c*32+f];
        vacc += vc * Wv[c*32+f];
    }
    vv[row*32+f] = vacc;
    float a1 = a[f], a2 = a[32+f];
    float pv  = hacc*(a1+a2);
    float q1v = kacc*a1;
    float q2v = kacc*a2;
    #pragma unroll
    for (int off=16; off; off>>=1){
        pv  += __shfl_down(pv,  off, 32);
        q1v += __shfl_down(q1v, off, 32);
        q2v += __shfl_down(q2v, off, 32);
    }
    if (f==0){ p[row]=pv; q1[row]=q1v; q2[row]=q2v; }
}

// ---------------- K2: per-batch softmax + reductions --------------------
// grid = B blocks x 256 thr. Produces r (shared att@vv row for i>=512),
// slo/shi (half-sums of vv), w01 (pair weights for i<512).
__global__ __launch_bounds__(256) void k_soft(
    const float* __restrict__ p,  const float* __restrict__ q1,
    const float* __restrict__ q2, const float* __restrict__ vv,
    float* __restrict__ r, float* __restrict__ slo, float* __restrict__ shi,
    float* __restrict__ w01)
{
    int b = blockIdx.x;
    int tid = threadIdx.x;
    __shared__ float e[1024];
    __shared__ float red[768];
    __shared__ float wred[8];
    const float* q1b = q1 + b*1024;
    const float* q2b = q2 + b*1024;

    float tloc[4]; float mloc = -1e30f;
    #pragma unroll
    for (int t=0; t<4; t++){
        int j  = tid + t*256;
        int j0 = (2*j)   & 1023;
        int j1 = (2*j+1) & 1023;
        float ts = leaky(q1b[j0] + q2b[j1]);
        tloc[t] = ts; mloc = fmaxf(mloc, ts);
    }
    #pragma unroll
    for (int off=32; off; off>>=1) mloc = fmaxf(mloc, __shfl_down(mloc, off, 64));
    if ((tid&63)==0) wred[tid>>6] = mloc;
    __syncthreads();
    float m = fmaxf(fmaxf(wred[0],wred[1]), fmaxf(wred[2],wred[3]));

    float ssum = 0.f;
    #pragma unroll
    for (int t=0; t<4; t++){
        float ev = __expf(tloc[t]-m);
        e[tid + t*256] = ev;
        ssum += ev;
    }
    #pragma unroll
    for (int off=32; off; off>>=1) ssum += __shfl_down(ssum, off, 64);
    if ((tid&63)==0) wred[4 + (tid>>6)] = ssum;   // disjoint slots from wred[0..3]
    __syncthreads();
    float invZ = 1.f/(wred[4]+wred[5]+wred[6]+wred[7]);

    int f = tid&31, g = tid>>5;
    const float* vvb = vv + b*32768;
    float racc=0.f, lacc=0.f, hacc=0.f;
    for (int j=g; j<1024; j+=8){
        float vf = vvb[j*32+f];
        racc += e[j]*vf;
        if (j<512) lacc += vf; else hacc += vf;
    }
    red[g*32+f]=racc; red[256+g*32+f]=lacc; red[512+g*32+f]=hacc;
    __syncthreads();
    if (g==0){
        float rs=0.f, ls=0.f, hs=0.f;
        #pragma unroll
        for (int gg=0; gg<8; gg++){
            rs += red[gg*32+f];
            ls += red[256+gg*32+f];
            hs += red[512+gg*32+f];
        }
        r  [b*32+f] = rs*invZ;
        slo[b*32+f] = ls;
        shi[b*32+f] = hs;
    }
    // pair weights for i<512 rows: softmax over {512 x s0, 512 x s1}
    const float* pb = p + b*1024;
    for (int i=tid; i<512; i+=256){
        float s0 = leaky(pb[2*i]);
        float s1 = leaky(pb[2*i+1]);
        float mm = fmaxf(s0,s1);
        float e0 = __expf(s0-mm), e1 = __expf(s1-mm);
        float d  = 1.f/(512.f*(e0+e1));
        w01[(b*512+i)*2  ] = e0*d;
        w01[(b*512+i)*2+1] = e1*d;
    }
}

// ---------------- K3: adj@vv + combine + leaky --------------------------
// grid = B*128 blocks x 256 thr; 8 rows/block, thread = (row, feature).
__global__ __launch_bounds__(256) void k_out(
    const float* __restrict__ adj,
    const float* __restrict__ vv,
    const float* __restrict__ r, const float* __restrict__ slo,
    const float* __restrict__ shi, const float* __restrict__ w01,
    float* __restrict__ out)
{
    int tid = threadIdx.x;
    int b     = blockIdx.x >> 7;
    int itile = blockIdx.x & 127;
    int rl = tid >> 5, f = tid & 31;
    int i  = itile*8 + rl;
    const float* adjrow = adj + i*1024;
    const float* vvb = vv + b*32768 + f;
    float acc = 0.f;
    for (int j0=0; j0<1024; j0+=4){
        float4 av = *reinterpret_cast<const float4*>(adjrow + j0);
        acc += av.x * vvb[(j0+0)*32];
        acc += av.y * vvb[(j0+1)*32];
        acc += av.z * vvb[(j0+2)*32];
        acc += av.w * vvb[(j0+3)*32];
    }
    float att;
    if (i < 512){
        float w0 = w01[(b*512+i)*2];
        float w1 = w01[(b*512+i)*2+1];
        att = w0*slo[b*32+f] + w1*shi[b*32+f];
    } else {
        att = r[b*32+f];
    }
    float o = 0.5f*(att + acc);
    out[(b*1024+i)*32 + f] = leaky(o);
}

extern "C" void kernel_launch(void* const* d_in, const int* in_sizes, int n_in,
                              void* d_out, int out_size, void* d_ws, size_t ws_size,
                              hipStream_t stream)
{
    const float* inp = (const float*)d_in[0];
    const float* kin = (const float*)d_in[1];
    const float* vin = (const float*)d_in[2];
    const float* adj = (const float*)d_in[3];
    const float* W   = (const float*)d_in[4];
    const float* Wk  = (const float*)d_in[5];
    const float* Wv  = (const float*)d_in[6];
    const float* a   = (const float*)d_in[7];
    float* out = (float*)d_out;

    float* ws  = (float*)d_ws;
    float* vv  = ws;            // 65536 floats
    float* p   = ws + 65536;    // 2048
    float* q1  = ws + 67584;    // 2048
    float* q2  = ws + 69632;    // 2048
    float* r   = ws + 71680;    // 64
    float* slo = ws + 71744;    // 64
    float* shi = ws + 71808;    // 64
    float* w01 = ws + 71872;    // 2048
    (void)in_sizes; (void)n_in; (void)out_size; (void)ws_size;

    hipLaunchKernelGGL(k_proj, dim3(256), dim3(256), 0, stream,
                       inp, kin, vin, W, Wk, Wv, a, vv, p, q1, q2);
    hipLaunchKernelGGL(k_soft, dim3(2), dim3(256), 0, stream,
                       p, q1, q2, vv, r, slo, shi, w01);
    hipLaunchKernelGGL(k_out, dim3(2*128), dim3(256), 0, stream,
                       adj, vv, r, slo, shi, w01, out);
}